// Round 9
// baseline (148.849 us; speedup 1.0000x reference)
//
#include <hip/hip_runtime.h>
#include <hip/hip_bf16.h>
#include <math.h>

// Problem constants (B=4, N=4096, C=128)
#define BATCH 4
#define SEQ   4096
#define CDIM  128
#define NROWS (BATCH * SEQ)        // 16384
#define KVB   32                   // KV rows per tile
#define NTILE (SEQ / KVB)          // 128 tiles per batch
#define KTILE_B 8192               // K tile: 32 x 128 fp16, swizzled
#define VTILE_B 8192               // V tile: d-major [d][k_lin] bf16, slot-swizzled
#define LOG2E 1.4426950408889634f

typedef __attribute__((ext_vector_type(4))) float    f32x4;
typedef __attribute__((ext_vector_type(8))) _Float16 half8;
typedef __attribute__((ext_vector_type(4))) short    bf16x4;
typedef __attribute__((ext_vector_type(8))) short    bf16x8;

__device__ __forceinline__ float bf2f(short s) {
  unsigned u = ((unsigned)(unsigned short)s) << 16;
  return __builtin_bit_cast(float, u);
}
__device__ __forceinline__ short f2bf(float f) {
  __hip_bfloat16 h = __float2bfloat16(f);
  return __builtin_bit_cast(short, h);
}
__device__ __forceinline__ float gelu_exact(float v) {
  return 0.5f * v * (1.0f + erff(v * 0.70710678118654752440f));
}
// Raw v_exp_f32 (2^x). s_nop 0 guards the trans-op consumer wait state.
__device__ __forceinline__ float exp2_hw(float x) {
  float r;
  asm("v_exp_f32 %0, %1\n\ts_nop 0" : "=v"(r) : "v"(x));
  return r;
}
// K tile swizzle (halfword offset within 4096-halfword tile image).
__device__ __forceinline__ int kswz_h(int r, int c) {
  int slot  = c >> 3;
  int slotp = (slot & 8) | ((slot ^ r) & 7);
  return r * 128 + slotp * 8 + (c & 7);
}
__device__ __forceinline__ void gl_lds16(const void* g, void* l) {
  __builtin_amdgcn_global_load_lds(
      (const __attribute__((address_space(1))) void*)g,
      (__attribute__((address_space(3))) void*)l, 16, 0, 0);
}

// ---------------------------------------------------------------------------
// Kernel 0: W -> fp16 fragment layout. wfrag[mat][nt][cc][lane][8]
// ---------------------------------------------------------------------------
__global__ void wprep_kernel(const float* __restrict__ Wq,
                             const float* __restrict__ Wk,
                             const float* __restrict__ Wv,
                             _Float16* __restrict__ wfrag) {
  int mat = blockIdx.y;
  const float* W = (mat == 0) ? Wq : ((mat == 1) ? Wk : Wv);
  int i = blockIdx.x * 256 + threadIdx.x;   // 0..16383
  int d = i >> 7, c = i & 127;
  int nt = d >> 4, qr = d & 15, cc = c >> 5, g = (c >> 3) & 3, j = c & 7;
  wfrag[(size_t)((((mat * 8 + nt) * 4 + cc) * 64) + 16 * g + qr) * 8 + j] =
      (_Float16)W[i];
}

// ---------------------------------------------------------------------------
// Kernel 1: QKV projection + exact GELU (fp16 MFMA), outputs bounced through
// LDS so all global stores are coalesced 16B. Q is pre-scaled by log2e.
// V image: [d][k_lin] bf16 (k-axis permuted so PV A-frag == p[0..7]),
// 16B slot swizzled by (d>>1)&3 (2-way bank aliasing = free).
// ---------------------------------------------------------------------------
__global__ __launch_bounds__(256) void proj_kernel(
    const float* __restrict__ x, const _Float16* __restrict__ wfrag,
    const float* __restrict__ bq, const float* __restrict__ bk,
    const float* __restrict__ bv,
    _Float16* __restrict__ qfrag, _Float16* __restrict__ kimg,
    short* __restrict__ vimg) {
  __shared__ __align__(16) char pls[16384];
  const int tid = threadIdx.x, wave = tid >> 6, lane = tid & 63;
  const int g = lane >> 4, qr = lane & 15;
  const int row0 = blockIdx.x * 64 + wave * 16;

  half8 xf[4];
#pragma unroll
  for (int c4 = 0; c4 < 4; ++c4) {
    const float* px = x + (size_t)(row0 + qr) * CDIM + 8 * g + 32 * c4;
    f32x4 a = *(const f32x4*)px;
    f32x4 bb = *(const f32x4*)(px + 4);
    half8 hx;
#pragma unroll
    for (int j = 0; j < 4; ++j) { hx[j] = (_Float16)a[j]; hx[4 + j] = (_Float16)bb[j]; }
    xf[c4] = hx;
  }

#pragma unroll
  for (int mat = 0; mat < 3; ++mat) {
    const float* bias = (mat == 0) ? bq : ((mat == 1) ? bk : bv);
    f32x4 acc[8];
#pragma unroll
    for (int nt = 0; nt < 8; ++nt) acc[nt] = (f32x4){0.f, 0.f, 0.f, 0.f};
#pragma unroll
    for (int nt = 0; nt < 8; ++nt)
#pragma unroll
      for (int c4 = 0; c4 < 4; ++c4) {
        half8 wf = *(const half8*)(wfrag +
            ((size_t)(((mat * 8 + nt) * 4 + c4) * 64) + lane) * 8);
        acc[nt] = __builtin_amdgcn_mfma_f32_16x16x32_f16(xf[c4], wf, acc[nt], 0, 0, 0);
      }

    short* ls = (short*)pls;
#pragma unroll
    for (int nt = 0; nt < 8; ++nt) {
      int col = 16 * nt + qr;
      float bi = bias[col];
#pragma unroll
      for (int r = 0; r < 4; ++r) {
        int rl = wave * 16 + 4 * g + r;        // row within block (0..63)
        float val = gelu_exact(acc[nt][r] + bi);
        int off;
        short sv;
        if (mat == 0) {
          int lane2 = ((col >> 3) & 3) * 16 + (rl & 15);
          off = ((wave * 4 + (col >> 5)) * 64 + lane2) * 8 + (col & 7);
          sv = __builtin_bit_cast(short, (_Float16)(val * LOG2E));
        } else if (mat == 1) {
          int tl = rl >> 5, rr = rl & 31;
          off = tl * 4096 + kswz_h(rr, col);
          sv = __builtin_bit_cast(short, (_Float16)val);
        } else {
          int tl = rl >> 5, rr = rl & 31;
          // k_lin such that k_phys(k_lin) = rr: g'=(rr>>2)&3, j=(rr&3)+4*(rr>>4)
          int klin = 8 * ((rr >> 2) & 3) + (rr & 3) + 4 * (rr >> 4);
          int slotp = (klin >> 3) ^ ((col >> 1) & 3);
          off = tl * 4096 + col * 32 + slotp * 8 + (klin & 7);
          sv = f2bf(val);
        }
        ls[off] = sv;
      }
    }
    __syncthreads();
    char* gdst = (mat == 0) ? (char*)qfrag + (size_t)blockIdx.x * 16384
               : (mat == 1) ? (char*)kimg + (size_t)blockIdx.x * 16384
                            : (char*)vimg + (size_t)blockIdx.x * 16384;
#pragma unroll
    for (int p = 0; p < 4; ++p)
      ((f32x4*)gdst)[tid + 256 * p] = ((const f32x4*)pls)[tid + 256 * p];
    __syncthreads();
  }
}

// ---------------------------------------------------------------------------
// Kernel 2: flash attention with counted-vmcnt pipeline (T3+T4).
// 3 K-buffers (distance 2) + 2 V-buffers (distance 1), 40 KB LDS.
// RACE-FIX vs round 8: each vmcnt wait sits BEFORE a barrier, so the barrier
// propagates per-wave staging completion block-wide (m201 discipline).
//   issue K(X+2) -> vmcnt(kw) -> barrier#1 -> issue V(X+1) -> QK+softmax
//   -> vmcnt(vw) -> barrier#2 -> PV
// Write-after-read is barrier-separated for both K (reads end before #2 of
// X-1; K-issue after it) and V (reads end before #1 of X; V-issue after it).
// Ledger (own ops; stageK/V = 2 each; issue order K0 V0 K1 | K2,V1 | K3,V2 |…):
//   kw: X=0:6  X=1:6  steady:6(no-op)  NT-2:4  NT-1:2
//   vw: X=0:6  X=1:4  steady:4         NT-2:2  NT-1:0
// ---------------------------------------------------------------------------
#define PHASE(KB, VB, KW, VW, IK, IV, VMK, VMV)                         \
  do {                                                                  \
    if (IK) stageK(KW);                                                 \
    asm volatile("s_waitcnt vmcnt(" VMK ")" ::: "memory");              \
    __builtin_amdgcn_s_barrier();                                       \
    if (IV) stageV(VW);                                                 \
    qk_sm(KB);                                                          \
    asm volatile("s_waitcnt vmcnt(" VMV ")" ::: "memory");              \
    __builtin_amdgcn_s_barrier();                                       \
    pv(VB);                                                             \
  } while (0)

template <int NSPLIT>
__global__ __launch_bounds__(256, 2) void attn_kernel(
    const _Float16* __restrict__ qfrag, const char* __restrict__ kimg,
    const char* __restrict__ vimg, short* __restrict__ pacc,
    float* __restrict__ pml) {
  __shared__ __align__(16) char smem[3 * KTILE_B + 2 * VTILE_B];   // 40 KB
  constexpr int NT = NTILE / NSPLIT;                // tiles per block
  static_assert((NT - 4) % 6 == 0, "steady loop needs (NT-4) % 6 == 0");
  constexpr int NSTEADY = (NT - 4) / 6;
  const int tid = threadIdx.x, wave = tid >> 6, lane = tid & 63;
  const int g = lane >> 4, qr = lane & 15;

  char* const kbuf0 = smem;
  char* const kbuf1 = smem + KTILE_B;
  char* const kbuf2 = smem + 2 * KTILE_B;
  char* const vbuf0 = smem + 3 * KTILE_B;
  char* const vbuf1 = smem + 3 * KTILE_B + VTILE_B;

  const int i = blockIdx.x;
  const int stream = i & (4 * NSPLIT - 1);  // stride 4*NSPLIT ≡ 0 mod 8 -> same XCD
  const int b = stream / NSPLIT, sp = stream % NSPLIT;
  const int qg = i / (4 * NSPLIT);          // 0..31 (128 q-rows each)

  // Q fragments for this wave's two 16-row tiles.
  const int t0 = b * 256 + qg * 8 + wave * 2;
  half8 qf[2][4];
#pragma unroll
  for (int qs = 0; qs < 2; ++qs)
#pragma unroll
    for (int c4 = 0; c4 < 4; ++c4)
      qf[qs][c4] = *(const half8*)(qfrag +
          ((size_t)((t0 + qs) * 4 + c4) * 64 + lane) * 8);

  // Precomputed LDS byte offsets (subtile selects fold into imm).
  int koff[4];
#pragma unroll
  for (int c4 = 0; c4 < 4; ++c4) {
    int slot = 4 * c4 + g;
    int slotp = (slot & 8) | ((slot ^ qr) & 7);
    koff[c4] = qr * 256 + slotp * 16;
  }
  const int voff = qr * 64 + ((g ^ ((qr >> 1) & 3)) << 4);  // + dt*1024 imm

  // Constant ones B-frag (bf16 1.0) for the row-sum MFMA.
  bf16x8 ones8;
#pragma unroll
  for (int j = 0; j < 8; ++j) ones8[j] = (short)0x3F80;

  // Running global KV pointers (advance per issue).
  const char* kp = kimg + ((size_t)b * NTILE + sp * NT) * KTILE_B + tid * 16;
  const char* vp = vimg + ((size_t)b * NTILE + sp * NT) * VTILE_B + tid * 16;

  auto stageK = [&](char* buf) {
    gl_lds16(kp,        buf + tid * 16);
    gl_lds16(kp + 4096, buf + 4096 + tid * 16);
    kp += KTILE_B;
  };
  auto stageV = [&](char* buf) {
    gl_lds16(vp,        buf + tid * 16);
    gl_lds16(vp + 4096, buf + 4096 + tid * 16);
    vp += VTILE_B;
  };

  f32x4 acc[2][8];
#pragma unroll
  for (int qs = 0; qs < 2; ++qs)
#pragma unroll
    for (int dt = 0; dt < 8; ++dt) acc[qs][dt] = (f32x4){0.f, 0.f, 0.f, 0.f};
  f32x4 lacc[2] = {(f32x4){0.f, 0.f, 0.f, 0.f}, (f32x4){0.f, 0.f, 0.f, 0.f}};
  float m[2] = {-INFINITY, -INFINITY};
  bf16x8 pf8[2];

  // ---- per-phase compute pieces ------------------------------------------
  auto qk_sm = [&](const char* kb) {
    f32x4 sA[2][2];
#pragma unroll
    for (int s = 0; s < 2; ++s) {
      half8 kf[4];
#pragma unroll
      for (int c4 = 0; c4 < 4; ++c4)
        kf[c4] = *(const half8*)(kb + koff[c4] + s * 4096);
      __builtin_amdgcn_s_setprio(1);
#pragma unroll
      for (int qs = 0; qs < 2; ++qs) {
        f32x4 tac = (f32x4){0.f, 0.f, 0.f, 0.f};
#pragma unroll
        for (int c4 = 0; c4 < 4; ++c4)
          tac = __builtin_amdgcn_mfma_f32_16x16x32_f16(kf[c4], qf[qs][c4], tac, 0, 0, 0);
        sA[qs][s] = tac;
      }
      __builtin_amdgcn_s_setprio(0);
    }
#pragma unroll
    for (int qs = 0; qs < 2; ++qs) {
      float tm = fmaxf(
          fmaxf(fmaxf(sA[qs][0][0], sA[qs][0][1]), fmaxf(sA[qs][0][2], sA[qs][0][3])),
          fmaxf(fmaxf(sA[qs][1][0], sA[qs][1][1]), fmaxf(sA[qs][1][2], sA[qs][1][3])));
      tm = fmaxf(tm, __shfl_xor(tm, 16, 64));
      tm = fmaxf(tm, __shfl_xor(tm, 32, 64));
      if (!__all(tm <= m[qs] + 8.0f)) {          // defer-max (p <= 2^8)
        float mn = fmaxf(m[qs], tm);
        float alpha = exp2_hw(m[qs] - mn);
        m[qs] = mn;
        float af[4];
#pragma unroll
        for (int r = 0; r < 4; ++r) af[r] = __shfl(alpha, 4 * g + r, 64);
#pragma unroll
        for (int dt = 0; dt < 8; ++dt)
#pragma unroll
          for (int r = 0; r < 4; ++r) acc[qs][dt][r] *= af[r];
#pragma unroll
        for (int r = 0; r < 4; ++r) lacc[qs][r] *= af[r];
      }
#pragma unroll
      for (int e = 0; e < 8; ++e)
        pf8[qs][e] = f2bf(exp2_hw(sA[qs][e >> 2][e & 3] - m[qs]));
    }
    // row-sum via ones-MFMA
    lacc[0] = __builtin_amdgcn_mfma_f32_16x16x32_bf16(pf8[0], ones8, lacc[0], 0, 0, 0);
    lacc[1] = __builtin_amdgcn_mfma_f32_16x16x32_bf16(pf8[1], ones8, lacc[1], 0, 0, 0);
  };

  auto pv = [&](const char* vb) {
#pragma unroll
    for (int dt = 0; dt < 8; ++dt) {
      bf16x8 v = *(const bf16x8*)(vb + voff + dt * 1024);
      __builtin_amdgcn_s_setprio(1);
      acc[0][dt] = __builtin_amdgcn_mfma_f32_16x16x32_bf16(pf8[0], v, acc[0][dt], 0, 0, 0);
      acc[1][dt] = __builtin_amdgcn_mfma_f32_16x16x32_bf16(pf8[1], v, acc[1][dt], 0, 0, 0);
      __builtin_amdgcn_s_setprio(0);
    }
  };

  // ---- pipeline ----------------------------------------------------------
  stageK(kbuf0); stageV(vbuf0); stageK(kbuf1);

  PHASE(kbuf0, vbuf0, kbuf2, vbuf1, true,  true,  "6", "6");   // X=0
  PHASE(kbuf1, vbuf1, kbuf0, vbuf0, true,  true,  "6", "4");   // X=1
#pragma unroll 1
  for (int it = 0; it < NSTEADY; ++it) {                       // X=2..NT-3
    PHASE(kbuf2, vbuf0, kbuf1, vbuf1, true, true, "6", "4");   // X%6==2
    PHASE(kbuf0, vbuf1, kbuf2, vbuf0, true, true, "6", "4");   // X%6==3
    PHASE(kbuf1, vbuf0, kbuf0, vbuf1, true, true, "6", "4");   // X%6==4
    PHASE(kbuf2, vbuf1, kbuf1, vbuf0, true, true, "6", "4");   // X%6==5
    PHASE(kbuf0, vbuf0, kbuf2, vbuf1, true, true, "6", "4");   // X%6==0
    PHASE(kbuf1, vbuf1, kbuf0, vbuf0, true, true, "6", "4");   // X%6==1
  }
  PHASE(kbuf2, vbuf0, kbuf0, vbuf1, false, true,  "4", "2");   // X=NT-2
  PHASE(kbuf0, vbuf1, kbuf0, vbuf0, false, false, "2", "0");   // X=NT-1

  // ---- store partials (bf16) ---------------------------------------------
  const int lrow0 = qg * 128 + wave * 32;
#pragma unroll
  for (int qs = 0; qs < 2; ++qs) {
#pragma unroll
    for (int dt = 0; dt < 8; ++dt)
#pragma unroll
      for (int r = 0; r < 4; ++r) {
        int grow = b * SEQ + lrow0 + qs * 16 + 4 * g + r;
        pacc[((size_t)sp * NROWS + grow) * CDIM + 16 * dt + qr] =
            f2bf(acc[qs][dt][r]);
      }
    if (g == 0) {    // lane qr holds row qr's max
      int grow = b * SEQ + lrow0 + qs * 16 + qr;
      pml[((size_t)sp * NROWS + grow) * 2 + 0] = m[qs];
    }
    if (qr == 0) {   // lane (g,0) holds rows 4g+r row-sums in lacc
#pragma unroll
      for (int r = 0; r < 4; ++r) {
        int grow = b * SEQ + lrow0 + qs * 16 + 4 * g + r;
        pml[((size_t)sp * NROWS + grow) * 2 + 1] = lacc[qs][r];
      }
    }
  }
}

// ---------------------------------------------------------------------------
// Kernel 3: combine the NSPLIT KV partials (log2-domain stats).
// ---------------------------------------------------------------------------
template <int NSPLIT>
__global__ __launch_bounds__(256) void combine_kernel(
    const short* __restrict__ pacc, const float* __restrict__ pml,
    float* __restrict__ out) {
  int idx = blockIdx.x * 256 + threadIdx.x;   // NROWS*16 threads
  int row = idx >> 4, c8 = idx & 15;
  float mm[NSPLIT], ll[NSPLIT];
  float M = -INFINITY;
#pragma unroll
  for (int h = 0; h < NSPLIT; ++h) {
    mm[h] = pml[((size_t)h * NROWS + row) * 2 + 0];
    ll[h] = pml[((size_t)h * NROWS + row) * 2 + 1];
    M = fmaxf(M, mm[h]);
  }
  float o[8];
#pragma unroll
  for (int j = 0; j < 8; ++j) o[j] = 0.f;
  float wl = 0.f;
#pragma unroll
  for (int h = 0; h < NSPLIT; ++h) {
    float w = exp2f(mm[h] - M);
    wl += w * ll[h];
    bf16x8 a = ((const bf16x8*)pacc)[((size_t)h * NROWS + row) * 16 + c8];
#pragma unroll
    for (int j = 0; j < 8; ++j) o[j] += w * bf2f(a[j]);
  }
  float inv = 1.0f / wl;
  f32x4 o0 = {o[0] * inv, o[1] * inv, o[2] * inv, o[3] * inv};
  f32x4 o1 = {o[4] * inv, o[5] * inv, o[6] * inv, o[7] * inv};
  ((f32x4*)out)[(size_t)row * 32 + c8 * 2 + 0] = o0;
  ((f32x4*)out)[(size_t)row * 32 + c8 * 2 + 1] = o1;
}

// ---------------------------------------------------------------------------
extern "C" void kernel_launch(void* const* d_in, const int* in_sizes, int n_in,
                              void* d_out, int out_size, void* d_ws, size_t ws_size,
                              hipStream_t stream) {
  const float* x  = (const float*)d_in[0];
  const float* Wq = (const float*)d_in[1];
  const float* bq = (const float*)d_in[2];
  const float* Wk = (const float*)d_in[3];
  const float* bk = (const float*)d_in[4];
  const float* Wv = (const float*)d_in[5];
  const float* bv = (const float*)d_in[6];
  float* out = (float*)d_out;

  char* ws = (char*)d_ws;
  _Float16* qfrag = (_Float16*)(ws);                       // 4 MB
  char*     kimg  = ws + (4u << 20);                       // 4 MB
  char*     vimg  = ws + (8u << 20);                       // 4 MB
  _Float16* wfrag = (_Float16*)(ws + (12u << 20));         // 96 KB
  char*     tail  = ws + (12u << 20) + (256u << 10);

  const size_t need8 = (12u << 20) + (256u << 10) +
                       (size_t)8 * NROWS * 8 + (size_t)8 * NROWS * CDIM * 2;

  wprep_kernel<<<dim3(64, 3), 256, 0, stream>>>(Wq, Wk, Wv, wfrag);
  proj_kernel<<<NROWS / 64, 256, 0, stream>>>(x, wfrag, bq, bk, bv,
                                              qfrag, (_Float16*)kimg, (short*)vimg);
  if (ws_size >= need8) {
    float* pml  = (float*)tail;                            // 1 MB
    short* pacc = (short*)(tail + (size_t)8 * NROWS * 8);  // 32 MB
    attn_kernel<8><<<1024, 256, 0, stream>>>(qfrag, kimg, vimg, pacc, pml);
    combine_kernel<8><<<NROWS * 16 / 256, 256, 0, stream>>>(pacc, pml, out);
  } else {
    float* pml  = (float*)tail;                            // 256 KB
    short* pacc = (short*)(tail + (size_t)2 * NROWS * 8);  // 8 MB
    attn_kernel<2><<<256, 256, 0, stream>>>(qfrag, kimg, vimg, pacc, pml);
    combine_kernel<2><<<NROWS * 16 / 256, 256, 0, stream>>>(pacc, pml, out);
  }
}

// Round 10
// 135.236 us; speedup vs baseline: 1.1007x; 1.1007x over previous
//
#include <hip/hip_runtime.h>
#include <hip/hip_bf16.h>
#include <math.h>

// Problem constants (B=4, N=4096, C=128)
#define BATCH 4
#define SEQ   4096
#define CDIM  128
#define NROWS (BATCH * SEQ)        // 16384
#define KVB   32                   // KV rows per tile
#define NTILE (SEQ / KVB)          // 128 tiles per batch
#define KTILE_B 8192               // K tile: 32 x 128 fp16, swizzled
#define VTILE_B 8192               // V tile: d-major [d][k_lin] bf16, slot-swizzled
#define LOG2E 1.4426950408889634f

typedef __attribute__((ext_vector_type(4))) float    f32x4;
typedef __attribute__((ext_vector_type(8))) _Float16 half8;
typedef __attribute__((ext_vector_type(4))) short    bf16x4;
typedef __attribute__((ext_vector_type(8))) short    bf16x8;

__device__ __forceinline__ float bf2f(short s) {
  unsigned u = ((unsigned)(unsigned short)s) << 16;
  return __builtin_bit_cast(float, u);
}
__device__ __forceinline__ short f2bf(float f) {
  __hip_bfloat16 h = __float2bfloat16(f);
  return __builtin_bit_cast(short, h);
}
__device__ __forceinline__ float gelu_exact(float v) {
  return 0.5f * v * (1.0f + erff(v * 0.70710678118654752440f));
}
// Raw v_exp_f32 (2^x). s_nop 0 guards the trans-op consumer wait state.
__device__ __forceinline__ float exp2_hw(float x) {
  float r;
  asm("v_exp_f32 %0, %1\n\ts_nop 0" : "=v"(r) : "v"(x));
  return r;
}
// K tile swizzle (halfword offset within 4096-halfword tile image).
__device__ __forceinline__ int kswz_h(int r, int c) {
  int slot  = c >> 3;
  int slotp = (slot & 8) | ((slot ^ r) & 7);
  return r * 128 + slotp * 8 + (c & 7);
}
__device__ __forceinline__ void gl_lds16(const void* g, void* l) {
  __builtin_amdgcn_global_load_lds(
      (const __attribute__((address_space(1))) void*)g,
      (__attribute__((address_space(3))) void*)l, 16, 0, 0);
}

// ---------------------------------------------------------------------------
// Kernel 0: W -> fp16 fragment layout. wfrag[mat][nt][cc][lane][8]
// ---------------------------------------------------------------------------
__global__ void wprep_kernel(const float* __restrict__ Wq,
                             const float* __restrict__ Wk,
                             const float* __restrict__ Wv,
                             _Float16* __restrict__ wfrag) {
  int mat = blockIdx.y;
  const float* W = (mat == 0) ? Wq : ((mat == 1) ? Wk : Wv);
  int i = blockIdx.x * 256 + threadIdx.x;   // 0..16383
  int d = i >> 7, c = i & 127;
  int nt = d >> 4, qr = d & 15, cc = c >> 5, g = (c >> 3) & 3, j = c & 7;
  wfrag[(size_t)((((mat * 8 + nt) * 4 + cc) * 64) + 16 * g + qr) * 8 + j] =
      (_Float16)W[i];
}

// ---------------------------------------------------------------------------
// Kernel 1: QKV projection + exact GELU (fp16 MFMA). One MATRIX per block
// (grid.y = mat) for 3x parallelism vs the serial mat-loop (x re-load is
// L2/L3-cached). Outputs bounced through LDS -> coalesced 16B stores.
// Q pre-scaled by log2e. V image: [d][k_lin] bf16 (k permuted so the PV
// A-frag == p[0..7]), 16B slot swizzled by (d>>1)&3 (2-way = free).
// ---------------------------------------------------------------------------
__global__ __launch_bounds__(256) void proj_kernel(
    const float* __restrict__ x, const _Float16* __restrict__ wfrag,
    const float* __restrict__ bq, const float* __restrict__ bk,
    const float* __restrict__ bv,
    _Float16* __restrict__ qfrag, _Float16* __restrict__ kimg,
    short* __restrict__ vimg) {
  __shared__ __align__(16) char pls[16384];
  const int tid = threadIdx.x, wave = tid >> 6, lane = tid & 63;
  const int g = lane >> 4, qr = lane & 15;
  const int row0 = blockIdx.x * 64 + wave * 16;
  const int mat = blockIdx.y;

  half8 xf[4];
#pragma unroll
  for (int c4 = 0; c4 < 4; ++c4) {
    const float* px = x + (size_t)(row0 + qr) * CDIM + 8 * g + 32 * c4;
    f32x4 a = *(const f32x4*)px;
    f32x4 bb = *(const f32x4*)(px + 4);
    half8 hx;
#pragma unroll
    for (int j = 0; j < 4; ++j) { hx[j] = (_Float16)a[j]; hx[4 + j] = (_Float16)bb[j]; }
    xf[c4] = hx;
  }

  const float* bias = (mat == 0) ? bq : ((mat == 1) ? bk : bv);
  f32x4 acc[8];
#pragma unroll
  for (int nt = 0; nt < 8; ++nt) acc[nt] = (f32x4){0.f, 0.f, 0.f, 0.f};
#pragma unroll
  for (int nt = 0; nt < 8; ++nt)
#pragma unroll
    for (int c4 = 0; c4 < 4; ++c4) {
      half8 wf = *(const half8*)(wfrag +
          ((size_t)(((mat * 8 + nt) * 4 + c4) * 64) + lane) * 8);
      acc[nt] = __builtin_amdgcn_mfma_f32_16x16x32_f16(xf[c4], wf, acc[nt], 0, 0, 0);
    }

  short* ls = (short*)pls;
#pragma unroll
  for (int nt = 0; nt < 8; ++nt) {
    int col = 16 * nt + qr;
    float bi = bias[col];
#pragma unroll
    for (int r = 0; r < 4; ++r) {
      int rl = wave * 16 + 4 * g + r;        // row within block (0..63)
      float val = gelu_exact(acc[nt][r] + bi);
      int off;
      short sv;
      if (mat == 0) {
        int lane2 = ((col >> 3) & 3) * 16 + (rl & 15);
        off = ((wave * 4 + (col >> 5)) * 64 + lane2) * 8 + (col & 7);
        sv = __builtin_bit_cast(short, (_Float16)(val * LOG2E));
      } else if (mat == 1) {
        int tl = rl >> 5, rr = rl & 31;
        off = tl * 4096 + kswz_h(rr, col);
        sv = __builtin_bit_cast(short, (_Float16)val);
      } else {
        int tl = rl >> 5, rr = rl & 31;
        // k_lin with k_phys(k_lin) = rr: klin = 8*g' + r + 4*s
        int klin = 8 * ((rr >> 2) & 3) + (rr & 3) + 4 * (rr >> 4);
        int slotp = (klin >> 3) ^ ((col >> 1) & 3);
        off = tl * 4096 + col * 32 + slotp * 8 + (klin & 7);
        sv = f2bf(val);
      }
      ls[off] = sv;
    }
  }
  __syncthreads();
  char* gdst = (mat == 0) ? (char*)qfrag + (size_t)blockIdx.x * 16384
             : (mat == 1) ? (char*)kimg + (size_t)blockIdx.x * 16384
                          : (char*)vimg + (size_t)blockIdx.x * 16384;
#pragma unroll
  for (int p = 0; p < 4; ++p)
    ((f32x4*)gdst)[tid + 256 * p] = ((const f32x4*)pls)[tid + 256 * p];
}

// ---------------------------------------------------------------------------
// Kernel 2: flash attention with counted-vmcnt pipeline (T3+T4).
// 3 K-buffers (distance 2) + 2 V-buffers (distance 1), 40 KB LDS.
//   issue K(X+2) -> vmcnt(kw) -> barrier#1 -> issue V(X+1) -> QK+softmax
//   -> vmcnt(vw) -> barrier#2 -> PV
// Ledger re-verified (phase X reads K(X) staged at X-2, V(X) staged at X-1):
//   kw: X=0:6 X=1:6 steady:6(no-op) NT-2:4 NT-1:2
//   vw: X=0:6 X=1:4 steady:4        NT-2:2 NT-1:0
// ROUND-10: cross-lane max is CONDITIONAL -- steady path has zero shfls;
// per-lane 8-max + __all test only. Shfl reduce runs on the rare rescale.
// ---------------------------------------------------------------------------
#define PHASE(KB, VB, KW, VW, IK, IV, VMK, VMV)                         \
  do {                                                                  \
    if (IK) stageK(KW);                                                 \
    asm volatile("s_waitcnt vmcnt(" VMK ")" ::: "memory");              \
    __builtin_amdgcn_s_barrier();                                       \
    if (IV) stageV(VW);                                                 \
    qk_sm(KB);                                                          \
    asm volatile("s_waitcnt vmcnt(" VMV ")" ::: "memory");              \
    __builtin_amdgcn_s_barrier();                                       \
    pv(VB);                                                             \
  } while (0)

template <int NSPLIT>
__global__ __launch_bounds__(256, 2) void attn_kernel(
    const _Float16* __restrict__ qfrag, const char* __restrict__ kimg,
    const char* __restrict__ vimg, short* __restrict__ pacc,
    float* __restrict__ pml) {
  __shared__ __align__(16) char smem[3 * KTILE_B + 2 * VTILE_B];   // 40 KB
  constexpr int NT = NTILE / NSPLIT;                // tiles per block
  static_assert((NT - 4) % 6 == 0, "steady loop needs (NT-4) % 6 == 0");
  constexpr int NSTEADY = (NT - 4) / 6;
  const int tid = threadIdx.x, wave = tid >> 6, lane = tid & 63;
  const int g = lane >> 4, qr = lane & 15;

  char* const kbuf0 = smem;
  char* const kbuf1 = smem + KTILE_B;
  char* const kbuf2 = smem + 2 * KTILE_B;
  char* const vbuf0 = smem + 3 * KTILE_B;
  char* const vbuf1 = smem + 3 * KTILE_B + VTILE_B;

  const int i = blockIdx.x;
  const int stream = i & (4 * NSPLIT - 1);  // stride 4*NSPLIT ≡ 0 mod 8 -> same XCD
  const int b = stream / NSPLIT, sp = stream % NSPLIT;
  const int qg = i / (4 * NSPLIT);          // 0..31 (128 q-rows each)

  // Q fragments for this wave's two 16-row tiles.
  const int t0 = b * 256 + qg * 8 + wave * 2;
  half8 qf[2][4];
#pragma unroll
  for (int qs = 0; qs < 2; ++qs)
#pragma unroll
    for (int c4 = 0; c4 < 4; ++c4)
      qf[qs][c4] = *(const half8*)(qfrag +
          ((size_t)((t0 + qs) * 4 + c4) * 64 + lane) * 8);

  // Precomputed LDS byte offsets (subtile selects fold into imm).
  int koff[4];
#pragma unroll
  for (int c4 = 0; c4 < 4; ++c4) {
    int slot = 4 * c4 + g;
    int slotp = (slot & 8) | ((slot ^ qr) & 7);
    koff[c4] = qr * 256 + slotp * 16;
  }
  const int voff = qr * 64 + ((g ^ ((qr >> 1) & 3)) << 4);  // + dt*1024 imm

  // Constant ones B-frag (bf16 1.0) for the row-sum MFMA.
  bf16x8 ones8;
#pragma unroll
  for (int j = 0; j < 8; ++j) ones8[j] = (short)0x3F80;

  // Running global KV pointers (advance per issue).
  const char* kp = kimg + ((size_t)b * NTILE + sp * NT) * KTILE_B + tid * 16;
  const char* vp = vimg + ((size_t)b * NTILE + sp * NT) * VTILE_B + tid * 16;

  auto stageK = [&](char* buf) {
    gl_lds16(kp,        buf + tid * 16);
    gl_lds16(kp + 4096, buf + 4096 + tid * 16);
    kp += KTILE_B;
  };
  auto stageV = [&](char* buf) {
    gl_lds16(vp,        buf + tid * 16);
    gl_lds16(vp + 4096, buf + 4096 + tid * 16);
    vp += VTILE_B;
  };

  f32x4 acc[2][8];
#pragma unroll
  for (int qs = 0; qs < 2; ++qs)
#pragma unroll
    for (int dt = 0; dt < 8; ++dt) acc[qs][dt] = (f32x4){0.f, 0.f, 0.f, 0.f};
  f32x4 lacc[2] = {(f32x4){0.f, 0.f, 0.f, 0.f}, (f32x4){0.f, 0.f, 0.f, 0.f}};
  float m[2] = {-INFINITY, -INFINITY};
  bf16x8 pf8[2];

  // ---- per-phase compute pieces ------------------------------------------
  auto qk_sm = [&](const char* kb) {
    f32x4 sA[2][2];
#pragma unroll
    for (int s = 0; s < 2; ++s) {
      half8 kf[4];
#pragma unroll
      for (int c4 = 0; c4 < 4; ++c4)
        kf[c4] = *(const half8*)(kb + koff[c4] + s * 4096);
      __builtin_amdgcn_s_setprio(1);
#pragma unroll
      for (int qs = 0; qs < 2; ++qs) {
        f32x4 tac = (f32x4){0.f, 0.f, 0.f, 0.f};
#pragma unroll
        for (int c4 = 0; c4 < 4; ++c4)
          tac = __builtin_amdgcn_mfma_f32_16x16x32_f16(kf[c4], qf[qs][c4], tac, 0, 0, 0);
        sA[qs][s] = tac;
      }
      __builtin_amdgcn_s_setprio(0);
    }
#pragma unroll
    for (int qs = 0; qs < 2; ++qs) {
      // Per-lane 8-element max only; cross-lane reduce on the rare path.
      float lmax = fmaxf(
          fmaxf(fmaxf(sA[qs][0][0], sA[qs][0][1]), fmaxf(sA[qs][0][2], sA[qs][0][3])),
          fmaxf(fmaxf(sA[qs][1][0], sA[qs][1][1]), fmaxf(sA[qs][1][2], sA[qs][1][3])));
      if (!__all(lmax <= m[qs] + 8.0f)) {        // defer-max (p <= 2^8)
        float tm = fmaxf(lmax, __shfl_xor(lmax, 16, 64));
        tm = fmaxf(tm, __shfl_xor(tm, 32, 64));  // row max across g-groups
        float mn = fmaxf(m[qs], tm);
        float alpha = exp2_hw(m[qs] - mn);
        m[qs] = mn;
        float af[4];
#pragma unroll
        for (int r = 0; r < 4; ++r) af[r] = __shfl(alpha, 4 * g + r, 64);
#pragma unroll
        for (int dt = 0; dt < 8; ++dt)
#pragma unroll
          for (int r = 0; r < 4; ++r) acc[qs][dt][r] *= af[r];
#pragma unroll
        for (int r = 0; r < 4; ++r) lacc[qs][r] *= af[r];
      }
#pragma unroll
      for (int e = 0; e < 8; ++e)
        pf8[qs][e] = f2bf(exp2_hw(sA[qs][e >> 2][e & 3] - m[qs]));
    }
    // row-sum via ones-MFMA
    lacc[0] = __builtin_amdgcn_mfma_f32_16x16x32_bf16(pf8[0], ones8, lacc[0], 0, 0, 0);
    lacc[1] = __builtin_amdgcn_mfma_f32_16x16x32_bf16(pf8[1], ones8, lacc[1], 0, 0, 0);
  };

  auto pv = [&](const char* vb) {
#pragma unroll
    for (int dt = 0; dt < 8; ++dt) {
      bf16x8 v = *(const bf16x8*)(vb + voff + dt * 1024);
      __builtin_amdgcn_s_setprio(1);
      acc[0][dt] = __builtin_amdgcn_mfma_f32_16x16x32_bf16(pf8[0], v, acc[0][dt], 0, 0, 0);
      acc[1][dt] = __builtin_amdgcn_mfma_f32_16x16x32_bf16(pf8[1], v, acc[1][dt], 0, 0, 0);
      __builtin_amdgcn_s_setprio(0);
    }
  };

  // ---- pipeline ----------------------------------------------------------
  stageK(kbuf0); stageV(vbuf0); stageK(kbuf1);

  PHASE(kbuf0, vbuf0, kbuf2, vbuf1, true,  true,  "6", "6");   // X=0
  PHASE(kbuf1, vbuf1, kbuf0, vbuf0, true,  true,  "6", "4");   // X=1
#pragma unroll 1
  for (int it = 0; it < NSTEADY; ++it) {                       // X=2..NT-3
    PHASE(kbuf2, vbuf0, kbuf1, vbuf1, true, true, "6", "4");   // X%6==2
    PHASE(kbuf0, vbuf1, kbuf2, vbuf0, true, true, "6", "4");   // X%6==3
    PHASE(kbuf1, vbuf0, kbuf0, vbuf1, true, true, "6", "4");   // X%6==4
    PHASE(kbuf2, vbuf1, kbuf1, vbuf0, true, true, "6", "4");   // X%6==5
    PHASE(kbuf0, vbuf0, kbuf2, vbuf1, true, true, "6", "4");   // X%6==0
    PHASE(kbuf1, vbuf1, kbuf0, vbuf0, true, true, "6", "4");   // X%6==1
  }
  PHASE(kbuf2, vbuf0, kbuf0, vbuf1, false, true,  "4", "2");   // X=NT-2
  PHASE(kbuf0, vbuf1, kbuf0, vbuf0, false, false, "2", "0");   // X=NT-1

  // ---- store partials (bf16) ---------------------------------------------
  const int lrow0 = qg * 128 + wave * 32;
#pragma unroll
  for (int qs = 0; qs < 2; ++qs) {
#pragma unroll
    for (int dt = 0; dt < 8; ++dt)
#pragma unroll
      for (int r = 0; r < 4; ++r) {
        int grow = b * SEQ + lrow0 + qs * 16 + 4 * g + r;
        pacc[((size_t)sp * NROWS + grow) * CDIM + 16 * dt + qr] =
            f2bf(acc[qs][dt][r]);
      }
    if (g == 0) {    // lane qr holds row qr's max
      int grow = b * SEQ + lrow0 + qs * 16 + qr;
      pml[((size_t)sp * NROWS + grow) * 2 + 0] = m[qs];
    }
    if (qr == 0) {   // lane (g,0) holds rows 4g+r row-sums in lacc
#pragma unroll
      for (int r = 0; r < 4; ++r) {
        int grow = b * SEQ + lrow0 + qs * 16 + 4 * g + r;
        pml[((size_t)sp * NROWS + grow) * 2 + 1] = lacc[qs][r];
      }
    }
  }
}

// ---------------------------------------------------------------------------
// Kernel 3: combine the NSPLIT KV partials (log2-domain stats).
// ---------------------------------------------------------------------------
template <int NSPLIT>
__global__ __launch_bounds__(256) void combine_kernel(
    const short* __restrict__ pacc, const float* __restrict__ pml,
    float* __restrict__ out) {
  int idx = blockIdx.x * 256 + threadIdx.x;   // NROWS*16 threads
  int row = idx >> 4, c8 = idx & 15;
  float mm[NSPLIT], ll[NSPLIT];
  float M = -INFINITY;
#pragma unroll
  for (int h = 0; h < NSPLIT; ++h) {
    mm[h] = pml[((size_t)h * NROWS + row) * 2 + 0];
    ll[h] = pml[((size_t)h * NROWS + row) * 2 + 1];
    M = fmaxf(M, mm[h]);
  }
  float o[8];
#pragma unroll
  for (int j = 0; j < 8; ++j) o[j] = 0.f;
  float wl = 0.f;
#pragma unroll
  for (int h = 0; h < NSPLIT; ++h) {
    float w = exp2f(mm[h] - M);
    wl += w * ll[h];
    bf16x8 a = ((const bf16x8*)pacc)[((size_t)h * NROWS + row) * 16 + c8];
#pragma unroll
    for (int j = 0; j < 8; ++j) o[j] += w * bf2f(a[j]);
  }
  float inv = 1.0f / wl;
  f32x4 o0 = {o[0] * inv, o[1] * inv, o[2] * inv, o[3] * inv};
  f32x4 o1 = {o[4] * inv, o[5] * inv, o[6] * inv, o[7] * inv};
  ((f32x4*)out)[(size_t)row * 32 + c8 * 2 + 0] = o0;
  ((f32x4*)out)[(size_t)row * 32 + c8 * 2 + 1] = o1;
}

// ---------------------------------------------------------------------------
extern "C" void kernel_launch(void* const* d_in, const int* in_sizes, int n_in,
                              void* d_out, int out_size, void* d_ws, size_t ws_size,
                              hipStream_t stream) {
  const float* x  = (const float*)d_in[0];
  const float* Wq = (const float*)d_in[1];
  const float* bq = (const float*)d_in[2];
  const float* Wk = (const float*)d_in[3];
  const float* bk = (const float*)d_in[4];
  const float* Wv = (const float*)d_in[5];
  const float* bv = (const float*)d_in[6];
  float* out = (float*)d_out;

  char* ws = (char*)d_ws;
  _Float16* qfrag = (_Float16*)(ws);                       // 4 MB
  char*     kimg  = ws + (4u << 20);                       // 4 MB
  char*     vimg  = ws + (8u << 20);                       // 4 MB
  _Float16* wfrag = (_Float16*)(ws + (12u << 20));         // 96 KB
  char*     tail  = ws + (12u << 20) + (256u << 10);

  const size_t need8 = (12u << 20) + (256u << 10) +
                       (size_t)8 * NROWS * 8 + (size_t)8 * NROWS * CDIM * 2;

  wprep_kernel<<<dim3(64, 3), 256, 0, stream>>>(Wq, Wk, Wv, wfrag);
  proj_kernel<<<dim3(NROWS / 64, 3), 256, 0, stream>>>(x, wfrag, bq, bk, bv,
                                                       qfrag, (_Float16*)kimg,
                                                       (short*)vimg);
  if (ws_size >= need8) {
    float* pml  = (float*)tail;                            // 1 MB
    short* pacc = (short*)(tail + (size_t)8 * NROWS * 8);  // 32 MB
    attn_kernel<8><<<1024, 256, 0, stream>>>(qfrag, kimg, vimg, pacc, pml);
    combine_kernel<8><<<NROWS * 16 / 256, 256, 0, stream>>>(pacc, pml, out);
  } else {
    float* pml  = (float*)tail;                            // 256 KB
    short* pacc = (short*)(tail + (size_t)2 * NROWS * 8);  // 8 MB
    attn_kernel<2><<<256, 256, 0, stream>>>(qfrag, kimg, vimg, pacc, pml);
    combine_kernel<2><<<NROWS * 16 / 256, 256, 0, stream>>>(pacc, pml, out);
  }
}